// Round 7
// baseline (286.853 us; speedup 1.0000x reference)
//
#include <hip/hip_runtime.h>
#include <hip/hip_bf16.h>

#define C_DIM 256
#define C8 32
#define N_DIM 4096
#define B_DIM 8
#define SPLIT 2
#define KEYS_PER (N_DIM / SPLIT)   // 2048
#define TILES (KEYS_PER / 64)      // 32

using bf16x8 = __attribute__((ext_vector_type(8))) __bf16;
using bf16x4 = __attribute__((ext_vector_type(4))) __bf16;
using f32x4  = __attribute__((ext_vector_type(4))) float;
using f32x16 = __attribute__((ext_vector_type(16))) float;
using uint2v = __attribute__((ext_vector_type(2))) unsigned;

#define LOG2E 1.44269504088896f
#define SHIFT_L2 17.3123404906675f   // 12 * log2(e)

// ---------------------------------------------------------------------------
// Kernel 0: x[b,c,n] f32  ->  xt[b,n,c] bf16   (LDS tile transpose)
// ---------------------------------------------------------------------------
__global__ __launch_bounds__(256) void k_transpose(
    const float* __restrict__ x, __bf16* __restrict__ xt)
{
    __shared__ float tile[64][65];
    int bid = blockIdx.x;
    int b  = bid >> 8;
    int ct = (bid >> 6) & 3;
    int nt = bid & 63;
    int c0 = ct * 64, n0 = nt * 64;
    int t = threadIdx.x;

    const float* xb = x + (size_t)b * C_DIM * N_DIM;
#pragma unroll
    for (int k = 0; k < 16; k++) {
        int idx = k * 256 + t;
        int i = idx >> 6, j = idx & 63;
        tile[i][j] = xb[(size_t)(c0 + i) * N_DIM + n0 + j];
    }
    __syncthreads();
    __bf16* xtb = xt + (size_t)b * N_DIM * C_DIM;
#pragma unroll
    for (int k = 0; k < 16; k++) {
        int idx = k * 256 + t;
        int nl = idx >> 6, cl = idx & 63;
        xtb[(size_t)(n0 + nl) * C_DIM + c0 + cl] = (__bf16)tile[cl][nl];
    }
}

// ---------------------------------------------------------------------------
// Kernel 1: QKV projection. Q rows pre-scaled by log2(e).
// ---------------------------------------------------------------------------
__global__ __launch_bounds__(256) void k_qkv(
    const float* __restrict__ Wq, const float* __restrict__ bq,
    const float* __restrict__ Wk, const float* __restrict__ bk,
    const float* __restrict__ Wv, const float* __restrict__ bv,
    const __bf16* __restrict__ xt,
    __bf16* __restrict__ Qt, __bf16* __restrict__ Kt, __bf16* __restrict__ Vb)
{
    int bid = blockIdx.x;
    int b   = bid / 320;
    int rem = bid % 320;
    int dt  = rem / 64;
    int nt  = rem % 64;
    int n0  = nt * 64;
    int wid  = threadIdx.x >> 6;
    int lane = threadIdx.x & 63;
    int lg = lane >> 4, li = lane & 15;
    int d0w = dt * 64 + wid * 16;

    int drow = d0w + li;
    const float* wrow;
    if (drow < 32)        wrow = Wq + drow * C_DIM;
    else if (drow < 64)   wrow = Wk + (drow - 32) * C_DIM;
    else                  wrow = Wv + (drow - 64) * C_DIM;

    const __bf16* xtb = xt + (size_t)b * N_DIM * C_DIM;

    f32x4 acc[4] = {};
#pragma unroll
    for (int ks = 0; ks < 8; ks++) {
        int c0 = ks * 32 + lg * 8;
        float4 w0 = *(const float4*)(wrow + c0);
        float4 w1 = *(const float4*)(wrow + c0 + 4);
        bf16x8 af;
        af[0] = (__bf16)w0.x; af[1] = (__bf16)w0.y;
        af[2] = (__bf16)w0.z; af[3] = (__bf16)w0.w;
        af[4] = (__bf16)w1.x; af[5] = (__bf16)w1.y;
        af[6] = (__bf16)w1.z; af[7] = (__bf16)w1.w;
#pragma unroll
        for (int ns = 0; ns < 4; ns++) {
            bf16x8 bfr = *(const bf16x8*)(xtb + (size_t)(n0 + ns * 16 + li) * C_DIM + ks * 32 + lg * 8);
            acc[ns] = __builtin_amdgcn_mfma_f32_16x16x32_bf16(af, bfr, acc[ns], 0, 0, 0);
        }
    }
#pragma unroll
    for (int r = 0; r < 4; r++) {
        int d = d0w + lg * 4 + r;
        float bias = (d < 32) ? bq[d] : (d < 64) ? bk[d - 32] : bv[d - 64];
#pragma unroll
        for (int ns = 0; ns < 4; ns++) {
            int n = n0 + ns * 16 + li;
            float v = acc[ns][r] + bias;
            if (d < 32)
                Qt[((size_t)b * N_DIM + n) * C8 + d] = (__bf16)(v * LOG2E);
            else if (d < 64)
                Kt[((size_t)b * N_DIM + n) * C8 + (d - 32)] = (__bf16)v;
            else
                Vb[((size_t)b * C_DIM + (d - 64)) * N_DIM + n] = (__bf16)v;
        }
    }
}

// ---------------------------------------------------------------------------
// helpers for the barrier-free attention
// ---------------------------------------------------------------------------
static __device__ __forceinline__ unsigned pack2(float a, float b) {
    union { __bf16 h[2]; unsigned u; } c;
    c.h[0] = (__bf16)a; c.h[1] = (__bf16)b; return c.u;
}
static __device__ __forceinline__ bf16x8 mkfrag(unsigned d0, unsigned d1, unsigned d2, unsigned d3) {
    union { unsigned u[4]; bf16x8 v; } r;
    r.u[0] = d0; r.u[1] = d1; r.u[2] = d2; r.u[3] = d3; return r.v;
}
static __device__ __forceinline__ uint2v plswap(unsigned a, unsigned b) {
#if __has_builtin(__builtin_amdgcn_permlane32_swap)
    return __builtin_amdgcn_permlane32_swap(a, b, false, false);
#else
    unsigned ax = (unsigned)__shfl_xor((int)a, 32);
    unsigned bx = (unsigned)__shfl_xor((int)b, 32);
    int hi = (threadIdx.x >> 5) & 1;
    uint2v r;
    r.x = hi ? bx : a;   // [a_lo | b_lo]
    r.y = hi ? b  : ax;  // [a_hi | b_hi]
    return r;
#endif
}
// S~ (K·Q^T) 32x32 C/D block -> exp2 -> two PV B-fragments (16-key slices).
// Row map: key_local = (r&3) + 8*(r>>2) + 4*hi.  permlane32_swap redistributes
// so lane hi' holds k = hi'*8+e of each slice. Also accumulates l partials.
static __device__ __forceinline__ void soft_pack(
    const f32x16& s, float& l, bf16x8& f0, bf16x8& f1)
{
    float p[16];
#pragma unroll
    for (int r = 0; r < 16; r++) p[r] = __builtin_amdgcn_exp2f(s[r] - SHIFT_L2);
    float lp = 0.f;
#pragma unroll
    for (int r = 0; r < 16; r++) lp += p[r];
    l += lp;
    unsigned a0 = pack2(p[0],  p[1]),  b0 = pack2(p[2],  p[3]);
    unsigned a1 = pack2(p[4],  p[5]),  b1 = pack2(p[6],  p[7]);
    unsigned a2 = pack2(p[8],  p[9]),  b2 = pack2(p[10], p[11]);
    unsigned a3 = pack2(p[12], p[13]), b3 = pack2(p[14], p[15]);
    uint2v rA0 = plswap(a0, a1), rB0 = plswap(b0, b1);
    uint2v rA1 = plswap(a2, a3), rB1 = plswap(b2, b3);
    f0 = mkfrag(rA0.x, rB0.x, rA0.y, rB0.y);   // keys 0..15 of the 32-block
    f1 = mkfrag(rA1.x, rB1.x, rA1.y, rB1.y);   // keys 16..31
}

// ---------------------------------------------------------------------------
// Kernel 2: barrier-free split-K flash attention.
// Wave = 64 queries x 64 channels x KEYS_PER keys. NO LDS, NO __syncthreads:
// swapped QK^T (mfma(K,Q), 32x32x16) puts P in registers in (almost) the PV
// B-frag layout; cvt_pk + permlane32_swap finishes it. 4 waves/block share
// nothing (wid = 64-channel slice). No-max softmax (exp2(s - shift)).
// ---------------------------------------------------------------------------
__global__ __launch_bounds__(256, 3) void k_attn(
    const __bf16* __restrict__ Qt, const __bf16* __restrict__ Kt,
    const __bf16* __restrict__ Vb,
    __bf16* __restrict__ Op, float* __restrict__ Ll)
{
    int bid = blockIdx.x;
    int b  = bid & 7;             // batch -> XCD affinity
    int qt = (bid >> 3) & 63;
    int sp = bid >> 9;            // key split 0..1
    int n0 = qt * 64;
    int wid = threadIdx.x >> 6;   // 64-channel slice
    int li  = threadIdx.x & 31;
    int hi  = (threadIdx.x >> 5) & 1;
    int c0  = wid * 64;
    int m0s = sp * KEYS_PER;

    const __bf16* Qb  = Qt + (size_t)b * N_DIM * C8;
    const __bf16* Kb  = Kt + (size_t)b * N_DIM * C8;
    const __bf16* Vbb = Vb + (size_t)b * C_DIM * N_DIM;

    // Q B-frags (held whole kernel): qfQB_DS ; B[k=d][j=query]
    const __bf16* Ql = Qb + ((size_t)(n0 + li) << 5) + (hi << 3);
    bf16x8 qf00 = *(const bf16x8*)(Ql);
    bf16x8 qf01 = *(const bf16x8*)(Ql + 16);
    bf16x8 qf10 = *(const bf16x8*)(Ql + 1024);
    bf16x8 qf11 = *(const bf16x8*)(Ql + 1024 + 16);

    // per-lane bases
    const __bf16* Kl  = Kb + ((size_t)(m0s + li) << 5) + (hi << 3);
    const __bf16* Vl0 = Vbb + (size_t)(c0 + li) * N_DIM + m0s + hi * 8;
    const __bf16* Vl1 = Vl0 + (size_t)32 * N_DIM;

    f32x16 acc00 = {}, acc01 = {}, acc10 = {}, acc11 = {};  // [cs][qb]
    float l0 = 0.f, l1 = 0.f;

    for (int t = 0; t < TILES; t++) {
        const __bf16* Ktile = Kl + (size_t)t * 2048;
#pragma unroll
        for (int kb = 0; kb < 2; kb++) {
            // K A-frags for this 32-key block (2 d-slices)
            bf16x8 k0 = *(const bf16x8*)(Ktile + kb * 1024);
            bf16x8 k1 = *(const bf16x8*)(Ktile + kb * 1024 + 16);
            // V A-frags (channel-slices x 16-key slices), issued early
            int vo = t * 64 + kb * 32;
            bf16x8 v00 = *(const bf16x8*)(Vl0 + vo);
            bf16x8 v01 = *(const bf16x8*)(Vl0 + vo + 16);
            bf16x8 v10 = *(const bf16x8*)(Vl1 + vo);
            bf16x8 v11 = *(const bf16x8*)(Vl1 + vo + 16);

            f32x16 z = {};
            // S~ = K·Q^T : rows=keys, cols=queries (col = lane&31)
            f32x16 s0 = __builtin_amdgcn_mfma_f32_32x32x16_bf16(k0, qf00, z, 0, 0, 0);
            s0 = __builtin_amdgcn_mfma_f32_32x32x16_bf16(k1, qf01, s0, 0, 0, 0);
            bf16x8 p00, p01;
            soft_pack(s0, l0, p00, p01);

            f32x16 s1 = __builtin_amdgcn_mfma_f32_32x32x16_bf16(k0, qf10, z, 0, 0, 0);
            s1 = __builtin_amdgcn_mfma_f32_32x32x16_bf16(k1, qf11, s1, 0, 0, 0);
            bf16x8 p10, p11;
            soft_pack(s1, l1, p10, p11);

            // PV: acc[cs][qb] += V[cs][slice] · P[slice][qb]
            acc00 = __builtin_amdgcn_mfma_f32_32x32x16_bf16(v00, p00, acc00, 0, 0, 0);
            acc00 = __builtin_amdgcn_mfma_f32_32x32x16_bf16(v01, p01, acc00, 0, 0, 0);
            acc01 = __builtin_amdgcn_mfma_f32_32x32x16_bf16(v00, p10, acc01, 0, 0, 0);
            acc01 = __builtin_amdgcn_mfma_f32_32x32x16_bf16(v01, p11, acc01, 0, 0, 0);
            acc10 = __builtin_amdgcn_mfma_f32_32x32x16_bf16(v10, p00, acc10, 0, 0, 0);
            acc10 = __builtin_amdgcn_mfma_f32_32x32x16_bf16(v11, p01, acc10, 0, 0, 0);
            acc11 = __builtin_amdgcn_mfma_f32_32x32x16_bf16(v10, p10, acc11, 0, 0, 0);
            acc11 = __builtin_amdgcn_mfma_f32_32x32x16_bf16(v11, p11, acc11, 0, 0, 0);
        }
    }

    // ---- epilogue: l (2-lane reduce over hi halves) + partial O
    size_t sb = (size_t)(sp * B_DIM + b);
    float lv0 = l0 + __shfl_xor(l0, 32);
    float lv1 = l1 + __shfl_xor(l1, 32);
    if (wid == 0 && hi == 0) {
        Ll[sb * N_DIM + n0 + li]      = lv0;
        Ll[sb * N_DIM + n0 + 32 + li] = lv1;
    }

#define STORE_ACC(A, CS, QB)                                                   \
    _Pragma("unroll")                                                          \
    for (int rg = 0; rg < 16; rg++) {                                          \
        int row = (rg & 3) + 8 * (rg >> 2) + 4 * hi;                           \
        Op[((size_t)sb * C_DIM + (c0 + CS * 32 + row)) * N_DIM                 \
           + (n0 + QB * 32 + li)] = (__bf16)A[rg];                             \
    }
    STORE_ACC(acc00, 0, 0)
    STORE_ACC(acc01, 0, 1)
    STORE_ACC(acc10, 1, 0)
    STORE_ACC(acc11, 1, 1)
#undef STORE_ACC
}

// ---------------------------------------------------------------------------
// Kernel 3: combine (sum partials, one gamma/L multiply, residual)
// ---------------------------------------------------------------------------
__global__ __launch_bounds__(256) void k_combine(
    const float* __restrict__ x, const __bf16* __restrict__ Op,
    const float* __restrict__ Ll,
    const float* __restrict__ gamma, float* __restrict__ out)
{
    int tid = blockIdx.x * 256 + threadIdx.x;   // 131072 total
    int n4 = tid & 1023;
    int cg = (tid >> 10) & 15;
    int b  = tid >> 14;
    int n  = n4 * 4;
    float g = gamma[0];

    float inv[4];
    {
        float L[4] = {0.f, 0.f, 0.f, 0.f};
#pragma unroll
        for (int s = 0; s < SPLIT; s++) {
            float4 t1 = *(const float4*)(Ll + ((size_t)(s * B_DIM + b) << 12) + n);
            L[0] += t1.x; L[1] += t1.y; L[2] += t1.z; L[3] += t1.w;
        }
#pragma unroll
        for (int j = 0; j < 4; j++) inv[j] = g / L[j];
    }

#pragma unroll 4
    for (int ci = 0; ci < 16; ci++) {
        int c = cg * 16 + ci;
        size_t base = (((size_t)b * C_DIM + c) << 12) + n;
        float4 xv = *(const float4*)(x + base);
        float o0 = 0.f, o1 = 0.f, o2 = 0.f, o3 = 0.f;
#pragma unroll
        for (int s = 0; s < SPLIT; s++) {
            bf16x4 p = *(const bf16x4*)(Op + (((size_t)(s * B_DIM + b) * C_DIM + c) << 12) + n);
            o0 += (float)p[0];
            o1 += (float)p[1];
            o2 += (float)p[2];
            o3 += (float)p[3];
        }
        float4 ov = { xv.x + o0 * inv[0], xv.y + o1 * inv[1],
                      xv.z + o2 * inv[2], xv.w + o3 * inv[3] };
        *(float4*)(out + base) = ov;
    }
}

// ---------------------------------------------------------------------------
extern "C" void kernel_launch(void* const* d_in, const int* in_sizes, int n_in,
                              void* d_out, int out_size, void* d_ws, size_t ws_size,
                              hipStream_t stream)
{
    const float* x     = (const float*)d_in[0];
    const float* Wq    = (const float*)d_in[1];
    const float* bq    = (const float*)d_in[2];
    const float* Wk    = (const float*)d_in[3];
    const float* bk    = (const float*)d_in[4];
    const float* Wv    = (const float*)d_in[5];
    const float* bv    = (const float*)d_in[6];
    const float* gamma = (const float*)d_in[7];
    float* out = (float*)d_out;

    char* ws = (char*)d_ws;
    const size_t MB = 1024 * 1024;
    __bf16* xt = (__bf16*)ws;                      // 16 MiB
    __bf16* Qt = (__bf16*)(ws + 16 * MB);          //  2 MiB
    __bf16* Kt = (__bf16*)(ws + 18 * MB);          //  2 MiB
    __bf16* Vb = (__bf16*)(ws + 20 * MB);          // 16 MiB
    __bf16* Op = (__bf16*)(ws + 36 * MB);          // 32 MiB (2 splits)
    float*  Ll = (float*)(ws + 100 * MB);          // 256 KiB

    k_transpose<<<2048, 256, 0, stream>>>(x, xt);
    k_qkv<<<2560, 256, 0, stream>>>(Wq, bq, Wk, bk, Wv, bv, xt, Qt, Kt, Vb);
    k_attn<<<512 * SPLIT, 256, 0, stream>>>(Qt, Kt, Vb, Op, Ll);
    k_combine<<<512, 256, 0, stream>>>(x, Op, Ll, gamma, out);
}